// Round 11
// baseline (873.541 us; speedup 1.0000x reference)
//
#include <hip/hip_runtime.h>

#define BB 2
#define CC 256
#define NN 3600
#define NCH 2
#define HO 473
#define WO 473
#define NP 3648          // NN padded to mult of 64 (K/stride padding)
#define NR 3712          // NN padded to mult of 128 (row padding)
#define LDT 72           // LDS tile row stride in u16 (16B-aligned)
#define NTI 29           // tiles of 128 covering NN
#define ZKS 6            // split-K slices for Z/conv GEMMs

typedef unsigned short u16;
typedef __attribute__((ext_vector_type(8))) short short8;
typedef __attribute__((ext_vector_type(4))) float f32x4;

static __device__ __forceinline__ u16 f2bf(float f) {
    unsigned u = __float_as_uint(f);
    unsigned r = (u + 0x7FFF + ((u >> 16) & 1)) >> 16;
    return (u16)r;
}
static __device__ __forceinline__ u16 f2h(float f) {
    _Float16 h = (_Float16)f;
    return __builtin_bit_cast(unsigned short, h);
}
static __device__ __forceinline__ float h2f(u16 u) {
    _Float16 h = __builtin_bit_cast(_Float16, u);
    return (float)h;
}

// ---------------------------------------------------------------------------
// 128x128 bf16 GEMM (gemm_we only): C[m][n] = sum_k A[m][k]*B[n][k], bf16 out
// ---------------------------------------------------------------------------
__global__ __launch_bounds__(256)
void gemm_we(const u16* __restrict__ vat, const u16* __restrict__ web,
             u16* __restrict__ wgtb)
{
    __shared__ u16 As[128 * LDT];
    __shared__ u16 Bs[128 * LDT];
    const u16* A = vat + (long)blockIdx.z * NR * CC;
    u16* Cp = wgtb + (long)blockIdx.z * NR * CC;

    const int t = threadIdx.x;
    const int w = t >> 6, lane = t & 63;
    const int mh = (w >> 1) * 64, nh = (w & 1) * 64;
    const int lm = lane & 15, quad = lane >> 4;
    const int m0 = blockIdx.y * 128, n0 = blockIdx.x * 128;

    f32x4 acc[4][4] = {};

    for (int k0 = 0; k0 < CC; k0 += 64) {
#pragma unroll
        for (int i = 0; i < 4; ++i) {
            int idx = i * 256 + t;
            int row = idx >> 3, c8 = (idx & 7) * 8;
            int rg = m0 + row;
            uint4 v = make_uint4(0u, 0u, 0u, 0u);
            if (rg < NN) v = *(const uint4*)(A + (long)rg * CC + k0 + c8);
            *(uint4*)(&As[row * LDT + c8]) = v;
            uint4 bv = make_uint4(0u, 0u, 0u, 0u);
            if (n0 + row < CC) bv = *(const uint4*)(web + (long)(n0 + row) * CC + k0 + c8);
            *(uint4*)(&Bs[row * LDT + c8]) = bv;
        }
        __syncthreads();
#pragma unroll
        for (int s = 0; s < 2; ++s) {
            short8 a[4], b[4];
#pragma unroll
            for (int i = 0; i < 4; ++i)
                a[i] = *(const short8*)(&As[(mh + i * 16 + lm) * LDT + s * 32 + quad * 8]);
#pragma unroll
            for (int j = 0; j < 4; ++j)
                b[j] = *(const short8*)(&Bs[(nh + j * 16 + lm) * LDT + s * 32 + quad * 8]);
#pragma unroll
            for (int i = 0; i < 4; ++i)
#pragma unroll
                for (int j = 0; j < 4; ++j)
                    acc[i][j] = __builtin_amdgcn_mfma_f32_16x16x32_bf16(a[i], b[j], acc[i][j], 0, 0, 0);
        }
        __syncthreads();
    }
#pragma unroll
    for (int i = 0; i < 4; ++i)
#pragma unroll
        for (int r = 0; r < 4; ++r) {
            int row = m0 + mh + i * 16 + quad * 4 + r;
            if (row < NN)
#pragma unroll
                for (int j = 0; j < 4; ++j) {
                    int col = n0 + nh + j * 16 + lm;
                    if (col < CC) Cp[(long)row * CC + col] = f2bf(acc[i][j][r]);
                }
        }
}

// ---------------------------------------------------------------------------
// S GEMM with fused softmax-stat partials; single fp16 output Sh[n][m].
// ---------------------------------------------------------------------------
__global__ __launch_bounds__(256)
void gemm_s_stats(const u16* __restrict__ A, const u16* __restrict__ B,
                  u16* __restrict__ Sh,
                  float* __restrict__ prowm, float* __restrict__ prows,
                  float* __restrict__ pcolm, float* __restrict__ pcols)
{
    __shared__ u16 smem[2 * 128 * LDT];     // As | Bs; reused as scratch later
    u16* As = smem;
    u16* Bs = smem + 128 * LDT;

    const int t = threadIdx.x;
    const int w = t >> 6, lane = t & 63;
    const int mh = (w >> 1) * 64, nh = (w & 1) * 64;
    const int lm = lane & 15, quad = lane >> 4;
    const int m0 = blockIdx.y * 128, n0 = blockIdx.x * 128;

    f32x4 acc[4][4] = {};

    for (int k0 = 0; k0 < CC; k0 += 64) {
#pragma unroll
        for (int i = 0; i < 4; ++i) {
            int idx = i * 256 + t;
            int row = idx >> 3, c8 = (idx & 7) * 8;
            uint4 v = make_uint4(0u, 0u, 0u, 0u);
            if (m0 + row < NN) v = *(const uint4*)(A + (long)(m0 + row) * CC + k0 + c8);
            *(uint4*)(&As[row * LDT + c8]) = v;
            uint4 bv = make_uint4(0u, 0u, 0u, 0u);
            if (n0 + row < NN) bv = *(const uint4*)(B + (long)(n0 + row) * CC + k0 + c8);
            *(uint4*)(&Bs[row * LDT + c8]) = bv;
        }
        __syncthreads();
#pragma unroll
        for (int s = 0; s < 2; ++s) {
            short8 a[4], b[4];
#pragma unroll
            for (int i = 0; i < 4; ++i)
                a[i] = *(const short8*)(&As[(mh + i * 16 + lm) * LDT + s * 32 + quad * 8]);
#pragma unroll
            for (int j = 0; j < 4; ++j)
                b[j] = *(const short8*)(&Bs[(nh + j * 16 + lm) * LDT + s * 32 + quad * 8]);
#pragma unroll
            for (int i = 0; i < 4; ++i)
#pragma unroll
                for (int j = 0; j < 4; ++j)
                    acc[i][j] = __builtin_amdgcn_mfma_f32_16x16x32_bf16(a[i], b[j], acc[i][j], 0, 0, 0);
        }
        __syncthreads();
    }

    // store S (fp16, row n contiguous in m)
#pragma unroll
    for (int i = 0; i < 4; ++i)
#pragma unroll
        for (int r = 0; r < 4; ++r) {
            int row = m0 + mh + i * 16 + quad * 4 + r;
            if (row < NN)
#pragma unroll
                for (int j = 0; j < 4; ++j) {
                    int col = n0 + nh + j * 16 + lm;
                    if (col < NN) Sh[(long)row * NP + col] = f2h(acc[i][j][r]);
                }
        }

    // ---- fused stats ----
    bool cval[4];
#pragma unroll
    for (int j = 0; j < 4; ++j) cval[j] = (n0 + nh + j * 16 + lm) < NN;

    float* sm = (float*)smem;         // 4 x [2][128] floats = 4 KB
    float* rowm = sm;
    float* rows_ = sm + 256;
    float* colm = sm + 512;
    float* cols_ = sm + 768;
    __syncthreads();

    // row stats (over this block's cols)
#pragma unroll
    for (int i = 0; i < 4; ++i)
#pragma unroll
        for (int r = 0; r < 4; ++r) {
            float m = -3.0e38f;
#pragma unroll
            for (int j = 0; j < 4; ++j) if (cval[j]) m = fmaxf(m, acc[i][j][r]);
            m = fmaxf(m, __shfl_xor(m, 1, 64));
            m = fmaxf(m, __shfl_xor(m, 2, 64));
            m = fmaxf(m, __shfl_xor(m, 4, 64));
            m = fmaxf(m, __shfl_xor(m, 8, 64));
            float s = 0.f;
#pragma unroll
            for (int j = 0; j < 4; ++j) if (cval[j]) s += __expf(acc[i][j][r] - m);
            s += __shfl_xor(s, 1, 64);
            s += __shfl_xor(s, 2, 64);
            s += __shfl_xor(s, 4, 64);
            s += __shfl_xor(s, 8, 64);
            if (lm == 0) {
                int rr = mh + i * 16 + quad * 4 + r;
                rowm[(w & 1) * 128 + rr] = m;
                rows_[(w & 1) * 128 + rr] = s;
            }
        }

    // col stats (over this block's rows)
#pragma unroll
    for (int j = 0; j < 4; ++j) {
        float m = -3.0e38f;
#pragma unroll
        for (int i = 0; i < 4; ++i)
#pragma unroll
            for (int r = 0; r < 4; ++r)
                if (m0 + mh + i * 16 + quad * 4 + r < NN) m = fmaxf(m, acc[i][j][r]);
        m = fmaxf(m, __shfl_xor(m, 16, 64));
        m = fmaxf(m, __shfl_xor(m, 32, 64));
        float s = 0.f;
#pragma unroll
        for (int i = 0; i < 4; ++i)
#pragma unroll
            for (int r = 0; r < 4; ++r)
                if (m0 + mh + i * 16 + quad * 4 + r < NN) s += __expf(acc[i][j][r] - m);
        s += __shfl_xor(s, 16, 64);
        s += __shfl_xor(s, 32, 64);
        if (quad == 0) {
            int ccl = nh + j * 16 + lm;
            colm[(w >> 1) * 128 + ccl] = m;
            cols_[(w >> 1) * 128 + ccl] = s;
        }
    }
    __syncthreads();

    if (t < 128) {
        float m1 = rowm[t], m2 = rowm[128 + t];
        float M = fmaxf(m1, m2);
        float s = rows_[t] * __expf(m1 - M) + rows_[128 + t] * __expf(m2 - M);
        if (m0 + t < NN) {
            prowm[(long)blockIdx.x * NR + m0 + t] = M;
            prows[(long)blockIdx.x * NR + m0 + t] = s;
        }
    } else {
        int c = t - 128;
        float m1 = colm[c], m2 = colm[128 + c];
        float M = fmaxf(m1, m2);
        float s = cols_[c] * __expf(m1 - M) + cols_[128 + c] * __expf(m2 - M);
        if (n0 + c < NN) {
            pcolm[(long)blockIdx.y * NR + n0 + c] = M;
            pcols[(long)blockIdx.y * NR + n0 + c] = s;
        }
    }
}

// merge NTI partials -> final stats. y=0: row (rmx/rsm); y=1: col (cmx/csm)
__global__ __launch_bounds__(256)
void stats_combine(const float* __restrict__ prowm, const float* __restrict__ prows,
                   const float* __restrict__ pcolm, const float* __restrict__ pcols,
                   float* __restrict__ rmx, float* __restrict__ rsm,
                   float* __restrict__ cmx, float* __restrict__ csm)
{
    int i = blockIdx.x * 256 + threadIdx.x;
    if (i >= NN) return;
    const float* pm = blockIdx.y ? pcolm : prowm;
    const float* ps = blockIdx.y ? pcols : prows;
    float m = -3.0e38f, s = 0.f;
#pragma unroll 4
    for (int tI = 0; tI < NTI; ++tI) {
        float m2 = pm[(long)tI * NR + i], s2 = ps[(long)tI * NR + i];
        float M = fmaxf(m, m2);
        s = s * __expf(m - M) + s2 * __expf(m2 - M);
        m = M;
    }
    if (blockIdx.y) { cmx[i] = m; csm[i] = s; }
    else            { rmx[i] = m; rsm[i] = s; }
}

// ---------------------------------------------------------------------------
// p_build2: dual-normalize + transpose in one pass over 64x64 tiles.
//   Pr (in place on Sh, bf16):  exp(v - rmx[n]) / rsm[n], pad cols m>=NN -> 0
//   PcT (into STh, bf16):       PcT[m][n] = exp(v - cmx[m]) / csm[m]
// ---------------------------------------------------------------------------
__global__ __launch_bounds__(256)
void p_build2(u16* __restrict__ Sh, u16* __restrict__ STh,
              const float* __restrict__ rmx, const float* __restrict__ rsm,
              const float* __restrict__ cmx, const float* __restrict__ csm)
{
    __shared__ u16 tile[64][65];       // [m_local][n_local], bf16 PcT staging
    const int m0 = blockIdx.x * 64;
    const int n0 = blockIdx.y * 64;
    const int t = threadIdx.x;

#pragma unroll
    for (int e = 0; e < 2; ++e) {
        int f = e * 256 + t;
        int i = f >> 3;                // n-local row
        int j8 = (f & 7) * 8;          // m-local col base
        int n = n0 + i;
        u16 pr[8];
        float rm = 0.f, ri = 0.f;
        uint4 hv = make_uint4(0u, 0u, 0u, 0u);
        if (n < NN) {
            rm = rmx[n]; ri = 1.f / rsm[n];
            hv = *(const uint4*)(Sh + (long)n * NP + m0 + j8);
        }
        const u16* hp = (const u16*)&hv;
#pragma unroll
        for (int q = 0; q < 8; ++q) {
            int m = m0 + j8 + q;
            float pc = 0.f;
            pr[q] = 0;
            if (n < NN && m < NN) {
                float v = h2f(hp[q]);
                pr[q] = f2bf(__expf(v - rm) * ri);
                pc = __expf(v - cmx[m]) * (1.f / csm[m]);
            }
            tile[j8 + q][i] = f2bf(pc);
        }
        if (n < NN) *(uint4*)(Sh + (long)n * NP + m0 + j8) = *(const uint4*)pr;
    }
    __syncthreads();
#pragma unroll
    for (int e = 0; e < 2; ++e) {
        int f = e * 256 + t;
        int i = f >> 3;                // m-local row
        int j8 = (f & 7) * 8;          // n-local col base
        int m = m0 + i;
        if (m < NN) {
            u16 o[8];
#pragma unroll
            for (int q = 0; q < 8; ++q) o[q] = tile[i][j8 + q];
            *(uint4*)(STh + (long)m * NP + n0 + j8) = *(const uint4*)o;
        }
    }
}

// ---------------------------------------------------------------------------
// Z GEMM, 128x128 tiles, pure bf16 staging, split-K + atomicAdd.
// OUTPUT TRANSPOSED: Z[pixel][channel] (row stride CC) so gates/convs consume
// directly. blockIdx: x = n-tile, y = ks, z = mtile*2 + branch.
// ---------------------------------------------------------------------------
__global__ __launch_bounds__(256, 4)
void gemm_z_128(const u16* __restrict__ vab_b, const u16* __restrict__ vbb_b,
                const u16* __restrict__ PT, const u16* __restrict__ P,
                float* __restrict__ Zb_b, float* __restrict__ Za_b)
{
    __shared__ u16 As[128 * LDT];
    __shared__ u16 Bs[128 * LDT];

    const int t = threadIdx.x;
    const int w = t >> 6, lane = t & 63;
    const int mh = (w >> 1) * 64, nh = (w & 1) * 64;
    const int lm = lane & 15, quad = lane >> 4;
    const int n0 = blockIdx.x * 128;
    const int ks = blockIdx.y;
    const int zz = blockIdx.z;
    const int branch = zz & 1;
    const int m0 = (zz >> 1) * 128;
    const u16* A = branch ? vbb_b : vab_b;
    const u16* B = branch ? P : PT;
    float* Cp = branch ? Za_b : Zb_b;

    const int base = 57 / ZKS, rem = 57 % ZKS;   // 9, 3
    const int it0 = ks * base + (ks < rem ? ks : rem);
    const int itn = base + (ks < rem ? 1 : 0);

    f32x4 acc[4][4] = {};

    for (int it = it0; it < it0 + itn; ++it) {
        const int k0 = it * 64;
#pragma unroll
        for (int i = 0; i < 4; ++i) {
            int idx = i * 256 + t;
            int row = idx >> 3, c8 = (idx & 7) * 8;
            uint4 v = *(const uint4*)(A + (long)(m0 + row) * NP + k0 + c8);
            *(uint4*)(&As[row * LDT + c8]) = v;
            int rg = n0 + row;
            uint4 bv = make_uint4(0u, 0u, 0u, 0u);
            if (rg < NN) bv = *(const uint4*)(B + (long)rg * NP + k0 + c8);
            *(uint4*)(&Bs[row * LDT + c8]) = bv;
        }
        __syncthreads();
#pragma unroll
        for (int s = 0; s < 2; ++s) {
            short8 a[4], b[4];
#pragma unroll
            for (int i = 0; i < 4; ++i)
                a[i] = *(const short8*)(&As[(mh + i * 16 + lm) * LDT + s * 32 + quad * 8]);
#pragma unroll
            for (int j = 0; j < 4; ++j)
                b[j] = *(const short8*)(&Bs[(nh + j * 16 + lm) * LDT + s * 32 + quad * 8]);
#pragma unroll
            for (int i = 0; i < 4; ++i)
#pragma unroll
                for (int j = 0; j < 4; ++j)
                    acc[i][j] = __builtin_amdgcn_mfma_f32_16x16x32_bf16(a[i], b[j], acc[i][j], 0, 0, 0);
        }
        __syncthreads();
    }

#pragma unroll
    for (int i = 0; i < 4; ++i)
#pragma unroll
        for (int r = 0; r < 4; ++r) {
            int row = m0 + mh + i * 16 + quad * 4 + r;     // channel
#pragma unroll
            for (int j = 0; j < 4; ++j) {
                int col = n0 + nh + j * 16 + lm;           // pixel
                if (col < NN)
                    atomicAdd(&Cp[(long)col * CC + row], acc[i][j][r]);
            }
        }
}

// ---------------------------------------------------------------------------
// Direct conv, 128x128 tiles, split-K + atomicAdd into Y (zero-initialized).
// blockIdx: x = p-tile, y = ks (ZKS), z = b*2 + mtile.
// ---------------------------------------------------------------------------
template<int CIN>
__global__ __launch_bounds__(256, 4)
void conv_128(const u16* __restrict__ W,
              const u16* __restrict__ P0, const u16* __restrict__ P1,
              const u16* __restrict__ P2, float* __restrict__ Y)
{
    const int KT = 9 * CIN;
    __shared__ u16 As[128 * LDT];
    __shared__ u16 Bs[128 * LDT];

    const int t = threadIdx.x;
    const int w = t >> 6, lane = t & 63;
    const int mh = (w >> 1) * 64, nh = (w & 1) * 64;
    const int lm = lane & 15, quad = lane >> 4;
    const int n0 = blockIdx.x * 128;
    const int ks = blockIdx.y;
    const int zz = blockIdx.z, b = zz >> 1;
    const int m0 = (zz & 1) * 128;
    const long pstride = (long)NR * CC;

    const int per = (KT / 64) / ZKS;
    const int it0 = ks * per;

    f32x4 acc[4][4] = {};

    for (int it = it0; it < it0 + per; ++it) {
        const int k0 = it * 64;
        int tap = k0 / CIN;
        int kloc = k0 - tap * CIN;
        int plane = kloc >> 8, cip = kloc & 255;
        int dh = tap / 3 - 1, dw = tap - (tap / 3) * 3 - 1;
        int off = dh * 60 + dw;
        const u16* src = (plane == 0) ? P0 : ((plane == 1) ? P1 : P2);
        src += (long)b * pstride + cip;

#pragma unroll
        for (int i = 0; i < 4; ++i) {
            int idx = i * 256 + t;
            int row = idx >> 3, c8 = (idx & 7) * 8;
            uint4 v = *(const uint4*)(W + (long)(m0 + row) * KT + k0 + c8);
            *(uint4*)(&As[row * LDT + c8]) = v;
            int p = n0 + row;
            uint4 bv = make_uint4(0u, 0u, 0u, 0u);
            if (p < NN) {
                int h = p / 60, wp = p - h * 60;
                int hh = h + dh, wq = wp + dw;
                if (hh >= 0 && hh < 60 && wq >= 0 && wq < 60)
                    bv = *(const uint4*)(src + (long)(p + off) * CC + c8);
            }
            *(uint4*)(&Bs[row * LDT + c8]) = bv;
        }
        __syncthreads();
#pragma unroll
        for (int s = 0; s < 2; ++s) {
            short8 a[4], bfr[4];
#pragma unroll
            for (int i = 0; i < 4; ++i)
                a[i] = *(const short8*)(&As[(mh + i * 16 + lm) * LDT + s * 32 + quad * 8]);
#pragma unroll
            for (int j = 0; j < 4; ++j)
                bfr[j] = *(const short8*)(&Bs[(nh + j * 16 + lm) * LDT + s * 32 + quad * 8]);
#pragma unroll
            for (int i = 0; i < 4; ++i)
#pragma unroll
                for (int j = 0; j < 4; ++j)
                    acc[i][j] = __builtin_amdgcn_mfma_f32_16x16x32_bf16(a[i], bfr[j], acc[i][j], 0, 0, 0);
        }
        __syncthreads();
    }

    float* out = Y + (long)b * CC * NN;
#pragma unroll
    for (int i = 0; i < 4; ++i)
#pragma unroll
        for (int r = 0; r < 4; ++r) {
            int row = m0 + mh + i * 16 + quad * 4 + r;
#pragma unroll
            for (int j = 0; j < 4; ++j) {
                int col = n0 + nh + j * 16 + lm;
                if (col < NN)
                    atomicAdd(&out[(long)row * NN + col], acc[i][j][r]);
            }
        }
}

// ---------------------------------------------------------------------------
// Converters / transposes
// ---------------------------------------------------------------------------
__global__ __launch_bounds__(256)
void cvt_we(const float* __restrict__ W, u16* __restrict__ O)
{
    int i = blockIdx.x * 256 + threadIdx.x;
    if (i < CC * CC) O[i] = f2bf(W[i]);
}

// V [b][256][3600] fp32 -> VT [b][3712][256] bf16; optionally also the
// NP-padded bf16 copy Vpad [b][256][3648] (zeros in pad).
__global__ __launch_bounds__(256)
void transpose_cvt(const float* __restrict__ V, u16* __restrict__ VT,
                   u16* __restrict__ Vpad)
{
    __shared__ float tile[64][65];
    int b = blockIdx.z, c0 = blockIdx.y * 64, n0 = blockIdx.x * 64;
    int t = threadIdx.x;
#pragma unroll
    for (int e = 0; e < 16; ++e) {
        int f = e * 256 + t; int i = f >> 6, j = f & 63;
        int n = n0 + j;
        float v = 0.f;
        if (n < NN) v = V[((long)b * CC + c0 + i) * NN + n];
        tile[i][j] = v;
        if (Vpad) Vpad[((long)b * CC + c0 + i) * NP + n] = f2bf(v);
    }
    __syncthreads();
#pragma unroll
    for (int e = 0; e < 16; ++e) {
        int f = e * 256 + t; int i = f >> 6, j = f & 63;
        int n = n0 + i;
        if (n < NN) VT[((long)b * NR + n) * CC + c0 + j] = f2bf(tile[j][i]);
    }
}

template<int CIN>
__global__ __launch_bounds__(256)
void cvt_convw(const float* __restrict__ W, u16* __restrict__ O)
{
    const int KT = 9 * CIN;
    long idx = (long)blockIdx.x * 256 + threadIdx.x;
    if (idx >= (long)CC * KT) return;
    int co = (int)(idx / KT);
    int r = (int)(idx % KT);
    int tap = r / CIN, ci = r % CIN;
    O[idx] = f2bf(W[((long)co * CIN + ci) * 9 + tap]);
}

// ---------------------------------------------------------------------------
// Fused gate: ZT fp32 [p][c] (stride CC) -> GT bf16 [p][c] (batch stride NR*CC)
// sg[p] = sigmoid(sum_c gw[c]*ZT[p][c]); GT[p][c] = bf16(ZT[p][c]*sg[p])
// grid (57, BB); 256 threads = 64 pixels x 4 channel-chunks.
// ---------------------------------------------------------------------------
__global__ __launch_bounds__(256)
void gate_fused(const float* __restrict__ ZT, const float* __restrict__ gw,
                u16* __restrict__ GT)
{
    int t = threadIdx.x;
    int px = t >> 2, ck = t & 3;
    int b = blockIdx.y;
    int p = blockIdx.x * 64 + px;
    const float* Zp = ZT + (long)b * CC * NN + (long)p * CC + ck * 64;
    bool valid = p < NN;
    float s = 0.f;
    if (valid) {
#pragma unroll
        for (int c = 0; c < 64; c += 4) {
            float4 v = *(const float4*)(Zp + c);
            float4 g = *(const float4*)(gw + ck * 64 + c);
            s += v.x * g.x + v.y * g.y + v.z * g.z + v.w * g.w;
        }
    }
    __shared__ float red[256];
    __shared__ float sg[64];
    red[t] = s;
    __syncthreads();
    if ((t & 3) == 0) {
        float tot = red[t] + red[t + 1] + red[t + 2] + red[t + 3];
        sg[t >> 2] = 1.f / (1.f + __expf(-tot));
    }
    __syncthreads();
    if (valid) {
        float sv = sg[px];
        u16* gp = GT + ((long)b * NR + p) * CC + ck * 64;
#pragma unroll
        for (int c = 0; c < 64; c += 4) {
            float4 v = *(const float4*)(Zp + c);
            u16 o[4];
            o[0] = f2bf(v.x * sv); o[1] = f2bf(v.y * sv);
            o[2] = f2bf(v.z * sv); o[3] = f2bf(v.w * sv);
            *(uint2*)(gp + c) = *(const uint2*)o;
        }
    }
}

// ---------------------------------------------------------------------------
// BatchNorm batch-stats -> scale/shift
// ---------------------------------------------------------------------------
__global__ __launch_bounds__(256)
void bn_stats_kernel(const float* __restrict__ Y, const float* __restrict__ g,
                     const float* __restrict__ beta, float* __restrict__ scale,
                     float* __restrict__ shift)
{
    int c = blockIdx.x, t = threadIdx.x;
    float s = 0.f, sq = 0.f;
    for (int b = 0; b < BB; ++b) {
        const float* p = Y + (long)b * CC * NN + (long)c * NN;
        for (int i = t; i < NN; i += 256) { float v = p[i]; s += v; sq += v * v; }
    }
    __shared__ float ls[256], lq[256];
    ls[t] = s; lq[t] = sq;
    __syncthreads();
    for (int off = 128; off > 0; off >>= 1) {
        if (t < off) { ls[t] += ls[t + off]; lq[t] += lq[t + off]; }
        __syncthreads();
    }
    if (t == 0) {
        const float inv = 1.f / (float)(BB * NN);
        float mean = ls[0] * inv;
        float var = fmaxf(lq[0] * inv - mean * mean, 0.f);
        float sc = g[c] * rsqrtf(var + 1e-5f);
        scale[c] = sc;
        shift[c] = beta[c] - mean * sc;
    }
}

// ---------------------------------------------------------------------------
// Fused BN-normalize + ReLU + 1x1 cls conv + bias
// ---------------------------------------------------------------------------
__global__ __launch_bounds__(256)
void cls_kernel(const float* __restrict__ Y, const float* __restrict__ scale,
                const float* __restrict__ shift, const float* __restrict__ cw,
                const float* __restrict__ cb, float* __restrict__ O)
{
    int t = threadIdx.x;
    int px = t & 63, ck = t >> 6;
    int b = blockIdx.y;
    int p = blockIdx.x * 64 + px;
    const float* Yb = Y + (long)b * CC * NN;
    float a0 = 0.f, a1 = 0.f;
    if (p < NN) {
        for (int c = ck * 64; c < ck * 64 + 64; ++c) {
            float v = Yb[(long)c * NN + p] * scale[c] + shift[c];
            v = fmaxf(v, 0.f);
            a0 += cw[c] * v;
            a1 += cw[CC + c] * v;
        }
    }
    __shared__ float r0[256], r1[256];
    r0[t] = a0; r1[t] = a1;
    __syncthreads();
    if (t < 64) {
        int pp = blockIdx.x * 64 + t;
        if (pp < NN) {
            float s0 = r0[t] + r0[t + 64] + r0[t + 128] + r0[t + 192];
            float s1 = r1[t] + r1[t + 64] + r1[t + 128] + r1[t + 192];
            O[(long)b * NCH * NN + pp] = s0 + cb[0];
            O[(long)b * NCH * NN + NN + pp] = s1 + cb[1];
        }
    }
}

// ---------------------------------------------------------------------------
// Bilinear resize 60x60 -> 473x473 (half-pixel, clamp) + sigmoid
// ---------------------------------------------------------------------------
__global__ __launch_bounds__(256)
void resize_sig_kernel(const float* __restrict__ I1, const float* __restrict__ I2,
                       float* __restrict__ O)
{
    const long HALF = (long)BB * NCH * HO * WO;
    long gid = (long)blockIdx.x * 256 + threadIdx.x;
    if (gid >= HALF) return;
    int half = blockIdx.y;
    const float* I = half ? I2 : I1;
    float* Op = O + half * HALF;

    int j = (int)(gid % WO);
    long r = gid / WO;
    int i = (int)(r % HO);
    int pc = (int)(r / HO);
    const float* ip = I + (long)pc * NN;

    const float SCL = 60.0f / 473.0f;
    float fy = (i + 0.5f) * SCL - 0.5f;
    float fx = (j + 0.5f) * SCL - 0.5f;
    int y0 = (int)floorf(fy);
    int x0 = (int)floorf(fx);
    float ty = fy - (float)y0;
    float tx = fx - (float)x0;
    int y0c = max(y0, 0), y1c = min(y0 + 1, 59);
    int x0c = max(x0, 0), x1c = min(x0 + 1, 59);
    float va = ip[y0c * 60 + x0c], vb = ip[y0c * 60 + x1c];
    float vc = ip[y1c * 60 + x0c], vd = ip[y1c * 60 + x1c];
    float v = (1.f - ty) * ((1.f - tx) * va + tx * vb) + ty * ((1.f - tx) * vc + tx * vd);
    Op[gid] = 1.f / (1.f + __expf(-v));
}

// ---------------------------------------------------------------------------
extern "C" void kernel_launch(void* const* d_in, const int* in_sizes, int n_in,
                              void* d_out, int out_size, void* d_ws, size_t ws_size,
                              hipStream_t stream)
{
    const float* V_a    = (const float*)d_in[0];
    const float* V_b    = (const float*)d_in[1];
    const float* D_a    = (const float*)d_in[2];
    const float* W_e    = (const float*)d_in[3];
    const float* gate_w = (const float*)d_in[4];
    const float* conv1_w = (const float*)d_in[5];
    const float* conv2_w = (const float*)d_in[6];
    const float* bn1_g = (const float*)d_in[7];
    const float* bn1_b = (const float*)d_in[8];
    const float* bn2_g = (const float*)d_in[9];
    const float* bn2_b = (const float*)d_in[10];
    const float* cls1_w = (const float*)d_in[11];
    const float* cls1_b = (const float*)d_in[12];
    const float* cls2_w = (const float*)d_in[13];
    const float* cls2_b = (const float*)d_in[14];
    float* out = (float*)d_out;

    // ---- workspace arena: ~143 MB (known-safe bound: 154.9 MB) ----
    size_t off = 0;
    char* wsb = (char*)d_ws;
    auto carve = [&](size_t bytes) -> char* {
        char* p = wsb + off; off += (bytes + 255) & ~(size_t)255; return p;
    };

    u16* Sh    = (u16*)carve((size_t)NN * NP * 2);         // 26.3 MB, per-batch
    u16* STh   = (u16*)carve((size_t)NN * NP * 2);         // 26.3 MB, per-batch
    u16* vab   = (u16*)carve((size_t)BB * CC * NP * 2);
    u16* vbb   = (u16*)carve((size_t)BB * CC * NP * 2);
    u16* vat   = (u16*)carve((size_t)BB * NR * CC * 2);
    u16* vbt   = (u16*)carve((size_t)BB * NR * CC * 2);
    u16* daT   = (u16*)carve((size_t)BB * NR * CC * 2);
    u16* gzaT  = (u16*)carve((size_t)BB * NR * CC * 2);
    u16* gzbT  = (u16*)carve((size_t)BB * NR * CC * 2);
    u16* wgtb  = (u16*)carve((size_t)BB * NR * CC * 2);
    u16* web   = (u16*)carve((size_t)CC * CC * 2);
    u16* wt1   = (u16*)carve((size_t)CC * 9 * 768 * 2);
    u16* wt2   = (u16*)carve((size_t)CC * 9 * 512 * 2);
    float* Za  = (float*)carve((size_t)BB * CC * NN * 4);  // [p][c] layout
    float* Zb  = (float*)carve((size_t)BB * CC * NN * 4);  // [p][c] layout
    float* y1  = (float*)carve((size_t)BB * CC * NN * 4);  // [c][p] layout
    float* y2  = (float*)carve((size_t)BB * CC * NN * 4);
    float* rmx = (float*)carve((size_t)BB * NN * 4);
    float* rsm = (float*)carve((size_t)BB * NN * 4);
    float* cmx = (float*)carve((size_t)BB * NN * 4);
    float* csm = (float*)carve((size_t)BB * NN * 4);
    float* prm = (float*)carve((size_t)NTI * NR * 4);
    float* prs = (float*)carve((size_t)NTI * NR * 4);
    float* pcm = (float*)carve((size_t)NTI * NR * 4);
    float* pcs = (float*)carve((size_t)NTI * NR * 4);
    float* c1o = (float*)carve((size_t)BB * NCH * NN * 4);
    float* c2o = (float*)carve((size_t)BB * NCH * NN * 4);

    dim3 blk(256);

    // zero-init all atomic accumulators (Za,Zb,y1,y2 contiguous)
    hipMemsetAsync(Za, 0, (size_t)4 * BB * CC * NN * 4, stream);

    // --- input conversions (padded copies fused into transposes) ---
    cvt_we<<<256, blk, 0, stream>>>(W_e, web);
    transpose_cvt<<<dim3(57, 4, BB), blk, 0, stream>>>(V_a, vat, vab);
    transpose_cvt<<<dim3(57, 4, BB), blk, 0, stream>>>(V_b, vbt, vbb);
    transpose_cvt<<<dim3(57, 4, BB), blk, 0, stream>>>(D_a, daT, nullptr);
    cvt_convw<768><<<(int)(((long)CC * 9 * 768 + 255) / 256), blk, 0, stream>>>(conv1_w, wt1);
    cvt_convw<512><<<(int)(((long)CC * 9 * 512 + 255) / 256), blk, 0, stream>>>(conv2_w, wt2);

    // --- weighted (both batches) ---
    gemm_we<<<dim3(2, NTI, BB), blk, 0, stream>>>(vat, web, wgtb);

    // --- attention, per batch ---
    for (int b = 0; b < BB; ++b) {
        const u16* wgtb_b = wgtb + (long)b * NR * CC;
        const u16* vbt_b  = vbt + (long)b * NR * CC;
        const u16* vab_b  = vab + (long)b * CC * NP;
        const u16* vbb_b  = vbb + (long)b * CC * NP;
        float* rmx_b = rmx + b * NN; float* rsm_b = rsm + b * NN;
        float* cmx_b = cmx + b * NN; float* csm_b = csm + b * NN;

        gemm_s_stats<<<dim3(NTI, NTI), blk, 0, stream>>>(
            wgtb_b, vbt_b, Sh, prm, prs, pcm, pcs);
        stats_combine<<<dim3((NN + 255) / 256, 2), blk, 0, stream>>>(
            prm, prs, pcm, pcs, rmx_b, rsm_b, cmx_b, csm_b);
        p_build2<<<dim3(57, 57), blk, 0, stream>>>(Sh, STh, rmx_b, rsm_b, cmx_b, csm_b);
        gemm_z_128<<<dim3(NTI, ZKS, 4), blk, 0, stream>>>(
            vab_b, vbb_b, STh, Sh,
            Zb + (long)b * CC * NN, Za + (long)b * CC * NN);
    }

    // --- fused gates: [p][c] fp32 -> scaled bf16 [p][c] ---
    gate_fused<<<dim3(57, BB), blk, 0, stream>>>(Za, gate_w, gzaT);
    gate_fused<<<dim3(57, BB), blk, 0, stream>>>(Zb, gate_w, gzbT);

    // --- convs: separate 128-tile direct split-K GEMMs, atomic into y1/y2 ---
    conv_128<768><<<dim3(NTI, ZKS, BB * 2), blk, 0, stream>>>(wt1, gzaT, vat, daT, y1);
    conv_128<512><<<dim3(NTI, ZKS, BB * 2), blk, 0, stream>>>(wt2, gzbT, vbt, vbt, y2);

    // --- BN + cls + resize --- (rmx/rsm/cmx/csm reused as scale/shift)
    bn_stats_kernel<<<256, blk, 0, stream>>>(y1, bn1_g, bn1_b, rmx, rsm);
    bn_stats_kernel<<<256, blk, 0, stream>>>(y2, bn2_g, bn2_b, cmx, csm);
    cls_kernel<<<dim3(57, BB), blk, 0, stream>>>(y1, rmx, rsm, cls1_w, cls1_b, c1o);
    cls_kernel<<<dim3(57, BB), blk, 0, stream>>>(y2, cmx, csm, cls2_w, cls2_b, c2o);

    resize_sig_kernel<<<dim3((int)(((long)BB * NCH * HO * WO + 255) / 256), 2), blk, 0, stream>>>(c1o, c2o, out);
}

// Round 12
// 672.064 us; speedup vs baseline: 1.2998x; 1.2998x over previous
//
#include <hip/hip_runtime.h>

#define BB 2
#define CC 256
#define NN 3600
#define NCH 2
#define HO 473
#define WO 473
#define NP 3648          // NN padded to mult of 64 (K/stride padding)
#define NR 3712          // NN padded to mult of 128 (row padding)
#define LDT 72           // LDS tile row stride in u16 (16B-aligned)
#define NTI 29           // tiles of 128 covering NN
#define ZKS 6            // split-K slices for Z/conv GEMMs

typedef unsigned short u16;
typedef __attribute__((ext_vector_type(8))) short short8;
typedef __attribute__((ext_vector_type(4))) float f32x4;

static __device__ __forceinline__ u16 f2bf(float f) {
    unsigned u = __float_as_uint(f);
    unsigned r = (u + 0x7FFF + ((u >> 16) & 1)) >> 16;
    return (u16)r;
}
static __device__ __forceinline__ u16 f2h(float f) {
    _Float16 h = (_Float16)f;
    return __builtin_bit_cast(unsigned short, h);
}
static __device__ __forceinline__ float h2f(u16 u) {
    _Float16 h = __builtin_bit_cast(_Float16, u);
    return (float)h;
}

// ---------------------------------------------------------------------------
// 128x128 bf16 GEMM (gemm_we only): C[m][n] = sum_k A[m][k]*B[n][k], bf16 out
// ---------------------------------------------------------------------------
__global__ __launch_bounds__(256)
void gemm_we(const u16* __restrict__ vat, const u16* __restrict__ web,
             u16* __restrict__ wgtb)
{
    __shared__ u16 As[128 * LDT];
    __shared__ u16 Bs[128 * LDT];
    const u16* A = vat + (long)blockIdx.z * NR * CC;
    u16* Cp = wgtb + (long)blockIdx.z * NR * CC;

    const int t = threadIdx.x;
    const int w = t >> 6, lane = t & 63;
    const int mh = (w >> 1) * 64, nh = (w & 1) * 64;
    const int lm = lane & 15, quad = lane >> 4;
    const int m0 = blockIdx.y * 128, n0 = blockIdx.x * 128;

    f32x4 acc[4][4] = {};

    for (int k0 = 0; k0 < CC; k0 += 64) {
#pragma unroll
        for (int i = 0; i < 4; ++i) {
            int idx = i * 256 + t;
            int row = idx >> 3, c8 = (idx & 7) * 8;
            int rg = m0 + row;
            uint4 v = make_uint4(0u, 0u, 0u, 0u);
            if (rg < NN) v = *(const uint4*)(A + (long)rg * CC + k0 + c8);
            *(uint4*)(&As[row * LDT + c8]) = v;
            uint4 bv = make_uint4(0u, 0u, 0u, 0u);
            if (n0 + row < CC) bv = *(const uint4*)(web + (long)(n0 + row) * CC + k0 + c8);
            *(uint4*)(&Bs[row * LDT + c8]) = bv;
        }
        __syncthreads();
#pragma unroll
        for (int s = 0; s < 2; ++s) {
            short8 a[4], b[4];
#pragma unroll
            for (int i = 0; i < 4; ++i)
                a[i] = *(const short8*)(&As[(mh + i * 16 + lm) * LDT + s * 32 + quad * 8]);
#pragma unroll
            for (int j = 0; j < 4; ++j)
                b[j] = *(const short8*)(&Bs[(nh + j * 16 + lm) * LDT + s * 32 + quad * 8]);
#pragma unroll
            for (int i = 0; i < 4; ++i)
#pragma unroll
                for (int j = 0; j < 4; ++j)
                    acc[i][j] = __builtin_amdgcn_mfma_f32_16x16x32_bf16(a[i], b[j], acc[i][j], 0, 0, 0);
        }
        __syncthreads();
    }
#pragma unroll
    for (int i = 0; i < 4; ++i)
#pragma unroll
        for (int r = 0; r < 4; ++r) {
            int row = m0 + mh + i * 16 + quad * 4 + r;
            if (row < NN)
#pragma unroll
                for (int j = 0; j < 4; ++j) {
                    int col = n0 + nh + j * 16 + lm;
                    if (col < CC) Cp[(long)row * CC + col] = f2bf(acc[i][j][r]);
                }
        }
}

// ---------------------------------------------------------------------------
// S GEMM with fused softmax-stat partials + dual fp16 output (S and S^T).
// ---------------------------------------------------------------------------
__global__ __launch_bounds__(256)
void gemm_s_stats(const u16* __restrict__ A, const u16* __restrict__ B,
                  u16* __restrict__ Sh, u16* __restrict__ STh,
                  float* __restrict__ prowm, float* __restrict__ prows,
                  float* __restrict__ pcolm, float* __restrict__ pcols)
{
    __shared__ u16 smem[2 * 128 * LDT];     // As | Bs; reused as scratch later
    u16* As = smem;
    u16* Bs = smem + 128 * LDT;

    const int t = threadIdx.x;
    const int w = t >> 6, lane = t & 63;
    const int mh = (w >> 1) * 64, nh = (w & 1) * 64;
    const int lm = lane & 15, quad = lane >> 4;
    const int m0 = blockIdx.y * 128, n0 = blockIdx.x * 128;

    f32x4 acc[4][4] = {};

    for (int k0 = 0; k0 < CC; k0 += 64) {
#pragma unroll
        for (int i = 0; i < 4; ++i) {
            int idx = i * 256 + t;
            int row = idx >> 3, c8 = (idx & 7) * 8;
            uint4 v = make_uint4(0u, 0u, 0u, 0u);
            if (m0 + row < NN) v = *(const uint4*)(A + (long)(m0 + row) * CC + k0 + c8);
            *(uint4*)(&As[row * LDT + c8]) = v;
            uint4 bv = make_uint4(0u, 0u, 0u, 0u);
            if (n0 + row < NN) bv = *(const uint4*)(B + (long)(n0 + row) * CC + k0 + c8);
            *(uint4*)(&Bs[row * LDT + c8]) = bv;
        }
        __syncthreads();
#pragma unroll
        for (int s = 0; s < 2; ++s) {
            short8 a[4], b[4];
#pragma unroll
            for (int i = 0; i < 4; ++i)
                a[i] = *(const short8*)(&As[(mh + i * 16 + lm) * LDT + s * 32 + quad * 8]);
#pragma unroll
            for (int j = 0; j < 4; ++j)
                b[j] = *(const short8*)(&Bs[(nh + j * 16 + lm) * LDT + s * 32 + quad * 8]);
#pragma unroll
            for (int i = 0; i < 4; ++i)
#pragma unroll
                for (int j = 0; j < 4; ++j)
                    acc[i][j] = __builtin_amdgcn_mfma_f32_16x16x32_bf16(a[i], b[j], acc[i][j], 0, 0, 0);
        }
        __syncthreads();
    }

    // store S (fp16, row n contiguous in m)
#pragma unroll
    for (int i = 0; i < 4; ++i)
#pragma unroll
        for (int r = 0; r < 4; ++r) {
            int row = m0 + mh + i * 16 + quad * 4 + r;
            if (row < NN)
#pragma unroll
                for (int j = 0; j < 4; ++j) {
                    int col = n0 + nh + j * 16 + lm;
                    if (col < NN) Sh[(long)row * NP + col] = f2h(acc[i][j][r]);
                }
        }

    // ---- fused stats ----
    bool cval[4];
#pragma unroll
    for (int j = 0; j < 4; ++j) cval[j] = (n0 + nh + j * 16 + lm) < NN;

    float* sm = (float*)smem;         // 4 x [2][128] floats = 4 KB
    float* rowm = sm;
    float* rows_ = sm + 256;
    float* colm = sm + 512;
    float* cols_ = sm + 768;
    __syncthreads();

    // row stats (over this block's cols)
#pragma unroll
    for (int i = 0; i < 4; ++i)
#pragma unroll
        for (int r = 0; r < 4; ++r) {
            float m = -3.0e38f;
#pragma unroll
            for (int j = 0; j < 4; ++j) if (cval[j]) m = fmaxf(m, acc[i][j][r]);
            m = fmaxf(m, __shfl_xor(m, 1, 64));
            m = fmaxf(m, __shfl_xor(m, 2, 64));
            m = fmaxf(m, __shfl_xor(m, 4, 64));
            m = fmaxf(m, __shfl_xor(m, 8, 64));
            float s = 0.f;
#pragma unroll
            for (int j = 0; j < 4; ++j) if (cval[j]) s += __expf(acc[i][j][r] - m);
            s += __shfl_xor(s, 1, 64);
            s += __shfl_xor(s, 2, 64);
            s += __shfl_xor(s, 4, 64);
            s += __shfl_xor(s, 8, 64);
            if (lm == 0) {
                int rr = mh + i * 16 + quad * 4 + r;
                rowm[(w & 1) * 128 + rr] = m;
                rows_[(w & 1) * 128 + rr] = s;
            }
        }

    // col stats (over this block's rows)
#pragma unroll
    for (int j = 0; j < 4; ++j) {
        float m = -3.0e38f;
#pragma unroll
        for (int i = 0; i < 4; ++i)
#pragma unroll
            for (int r = 0; r < 4; ++r)
                if (m0 + mh + i * 16 + quad * 4 + r < NN) m = fmaxf(m, acc[i][j][r]);
        m = fmaxf(m, __shfl_xor(m, 16, 64));
        m = fmaxf(m, __shfl_xor(m, 32, 64));
        float s = 0.f;
#pragma unroll
        for (int i = 0; i < 4; ++i)
#pragma unroll
            for (int r = 0; r < 4; ++r)
                if (m0 + mh + i * 16 + quad * 4 + r < NN) s += __expf(acc[i][j][r] - m);
        s += __shfl_xor(s, 16, 64);
        s += __shfl_xor(s, 32, 64);
        if (quad == 0) {
            int ccl = nh + j * 16 + lm;
            colm[(w >> 1) * 128 + ccl] = m;
            cols_[(w >> 1) * 128 + ccl] = s;
        }
    }
    __syncthreads();

    if (t < 128) {
        float m1 = rowm[t], m2 = rowm[128 + t];
        float M = fmaxf(m1, m2);
        float s = rows_[t] * __expf(m1 - M) + rows_[128 + t] * __expf(m2 - M);
        if (m0 + t < NN) {
            prowm[(long)blockIdx.x * NR + m0 + t] = M;
            prows[(long)blockIdx.x * NR + m0 + t] = s;
        }
    } else {
        int c = t - 128;
        float m1 = colm[c], m2 = colm[128 + c];
        float M = fmaxf(m1, m2);
        float s = cols_[c] * __expf(m1 - M) + cols_[128 + c] * __expf(m2 - M);
        if (n0 + c < NN) {
            pcolm[(long)blockIdx.y * NR + n0 + c] = M;
            pcols[(long)blockIdx.y * NR + n0 + c] = s;
        }
    }

    // ---- S^T via LDS transpose: tr[m_local][n_local], stride 136 ----
    __syncthreads();
    u16* tr = smem;                   // 128*136 u16 = 33.8 KB
#pragma unroll
    for (int i = 0; i < 4; ++i)
#pragma unroll
        for (int j = 0; j < 4; ++j)
#pragma unroll
            for (int r = 0; r < 4; ++r)
                tr[(nh + j * 16 + lm) * 136 + (mh + i * 16 + quad * 4 + r)] = f2h(acc[i][j][r]);
    __syncthreads();
    {
        int row = t >> 1, hf = t & 1;
        int mg = n0 + row;
        if (mg < NN) {
#pragma unroll
            for (int q = 0; q < 8; ++q) {
                int cb = m0 + hf * 64 + q * 8;
                if (cb < NN)
                    *(uint4*)(&STh[(long)mg * NP + cb]) =
                        *(const uint4*)(&tr[row * 136 + hf * 64 + q * 8]);
            }
        }
    }
}

// merge NTI partials -> final stats. y=0: row (rmx/rsm); y=1: col (cmx/csm)
__global__ __launch_bounds__(256)
void stats_combine(const float* __restrict__ prowm, const float* __restrict__ prows,
                   const float* __restrict__ pcolm, const float* __restrict__ pcols,
                   float* __restrict__ rmx, float* __restrict__ rsm,
                   float* __restrict__ cmx, float* __restrict__ csm)
{
    int i = blockIdx.x * 256 + threadIdx.x;
    if (i >= NN) return;
    const float* pm = blockIdx.y ? pcolm : prowm;
    const float* ps = blockIdx.y ? pcols : prows;
    float m = -3.0e38f, s = 0.f;
#pragma unroll 4
    for (int tI = 0; tI < NTI; ++tI) {
        float m2 = pm[(long)tI * NR + i], s2 = ps[(long)tI * NR + i];
        float M = fmaxf(m, m2);
        s = s * __expf(m - M) + s2 * __expf(m2 - M);
        m = M;
    }
    if (blockIdx.y) { cmx[i] = m; csm[i] = s; }
    else            { rmx[i] = m; rsm[i] = s; }
}

// ---------------------------------------------------------------------------
// In-place P build: fp16 S row -> bf16 exp(v - mx[row]) / sm[row]; pad cols
// zeroed. blockIdx.x = row; blockIdx.y: 0 = Sh (row stats), 1 = STh (col stats)
// ---------------------------------------------------------------------------
__global__ __launch_bounds__(256)
void p_build(u16* __restrict__ Sh, u16* __restrict__ STh,
             const float* __restrict__ rmx, const float* __restrict__ rsm,
             const float* __restrict__ cmx, const float* __restrict__ csm)
{
    int r = blockIdx.x;
    u16* M = blockIdx.y ? STh : Sh;
    const float* mx = blockIdx.y ? cmx : rmx;
    const float* sm = blockIdx.y ? csm : rsm;
    float mv = mx[r];
    float inv = 1.f / sm[r];
    u16* row = M + (long)r * NP;
    int t = threadIdx.x;
    for (int c0 = t * 8; c0 < NP; c0 += 2048) {
        uint4 hv = *(const uint4*)(row + c0);
        const u16* hp = (const u16*)&hv;
        u16 o[8];
#pragma unroll
        for (int e = 0; e < 8; ++e) {
            int c = c0 + e;
            o[e] = (c < NN) ? f2bf(__expf(h2f(hp[e]) - mv) * inv) : (u16)0;
        }
        *(uint4*)(row + c0) = *(const uint4*)o;
    }
}

// ---------------------------------------------------------------------------
// Z GEMM, 128x128 tiles, pure bf16 staging, split-K + atomicAdd ([c][p],
// coalesced). blockIdx: x = n-tile, y = ks, z = mtile*2 + branch.
// ---------------------------------------------------------------------------
__global__ __launch_bounds__(256, 4)
void gemm_z_128(const u16* __restrict__ vab_b, const u16* __restrict__ vbb_b,
                const u16* __restrict__ PT, const u16* __restrict__ P,
                float* __restrict__ Zb_b, float* __restrict__ Za_b)
{
    __shared__ u16 As[128 * LDT];
    __shared__ u16 Bs[128 * LDT];

    const int t = threadIdx.x;
    const int w = t >> 6, lane = t & 63;
    const int mh = (w >> 1) * 64, nh = (w & 1) * 64;
    const int lm = lane & 15, quad = lane >> 4;
    const int n0 = blockIdx.x * 128;
    const int ks = blockIdx.y;
    const int zz = blockIdx.z;
    const int branch = zz & 1;
    const int m0 = (zz >> 1) * 128;
    const u16* A = branch ? vbb_b : vab_b;
    const u16* B = branch ? P : PT;
    float* Cp = branch ? Za_b : Zb_b;

    const int base = 57 / ZKS, rem = 57 % ZKS;   // 9, 3
    const int it0 = ks * base + (ks < rem ? ks : rem);
    const int itn = base + (ks < rem ? 1 : 0);

    f32x4 acc[4][4] = {};

    for (int it = it0; it < it0 + itn; ++it) {
        const int k0 = it * 64;
#pragma unroll
        for (int i = 0; i < 4; ++i) {
            int idx = i * 256 + t;
            int row = idx >> 3, c8 = (idx & 7) * 8;
            uint4 v = *(const uint4*)(A + (long)(m0 + row) * NP + k0 + c8);
            *(uint4*)(&As[row * LDT + c8]) = v;
            int rg = n0 + row;
            uint4 bv = make_uint4(0u, 0u, 0u, 0u);
            if (rg < NN) bv = *(const uint4*)(B + (long)rg * NP + k0 + c8);
            *(uint4*)(&Bs[row * LDT + c8]) = bv;
        }
        __syncthreads();
#pragma unroll
        for (int s = 0; s < 2; ++s) {
            short8 a[4], b[4];
#pragma unroll
            for (int i = 0; i < 4; ++i)
                a[i] = *(const short8*)(&As[(mh + i * 16 + lm) * LDT + s * 32 + quad * 8]);
#pragma unroll
            for (int j = 0; j < 4; ++j)
                b[j] = *(const short8*)(&Bs[(nh + j * 16 + lm) * LDT + s * 32 + quad * 8]);
#pragma unroll
            for (int i = 0; i < 4; ++i)
#pragma unroll
                for (int j = 0; j < 4; ++j)
                    acc[i][j] = __builtin_amdgcn_mfma_f32_16x16x32_bf16(a[i], b[j], acc[i][j], 0, 0, 0);
        }
        __syncthreads();
    }

#pragma unroll
    for (int i = 0; i < 4; ++i)
#pragma unroll
        for (int r = 0; r < 4; ++r) {
            int row = m0 + mh + i * 16 + quad * 4 + r;
#pragma unroll
            for (int j = 0; j < 4; ++j) {
                int col = n0 + nh + j * 16 + lm;
                if (col < NN)
                    atomicAdd(&Cp[(long)row * NN + col], acc[i][j][r]);
            }
        }
}

// ---------------------------------------------------------------------------
// Both direct convs, one launch, XCD-grouped remap: linear block id L;
// combo = L % 8 (conv/batch/mtile — pins each combo's working set to one XCD
// under round-robin dispatch), (p-tile, ks) = L / 8.
// 128x128 tiles, split-K + atomicAdd. Y zero-initialized.
// ---------------------------------------------------------------------------
__global__ __launch_bounds__(256, 4)
void conv_both(const u16* __restrict__ W1, const u16* __restrict__ W2,
               const u16* __restrict__ gzaT, const u16* __restrict__ vat,
               const u16* __restrict__ daT, const u16* __restrict__ gzbT,
               const u16* __restrict__ vbt,
               float* __restrict__ y1, float* __restrict__ y2)
{
    __shared__ u16 As[128 * LDT];
    __shared__ u16 Bs[128 * LDT];

    const int t = threadIdx.x;
    const int w = t >> 6, lane = t & 63;
    const int mh = (w >> 1) * 64, nh = (w & 1) * 64;
    const int lm = lane & 15, quad = lane >> 4;

    const long L = blockIdx.x + (long)NTI * (blockIdx.y + (long)ZKS * blockIdx.z);
    const int combo = (int)(L & 7);
    const long rest = L >> 3;                   // 0..173
    const int ks = (int)(rest % ZKS);
    const int px = (int)(rest / ZKS);           // 0..28
    const int which = combo >> 2;
    const int b = (combo >> 1) & 1;
    const int m0 = (combo & 1) * 128;
    const int n0 = px * 128;

    const int CIN = which ? 512 : 768;
    const int KT = 9 * CIN;
    const u16* W = which ? W2 : W1;
    const u16* P0 = which ? gzbT : gzaT;
    const u16* P1 = which ? vbt : vat;
    const u16* P2 = which ? vbt : daT;
    float* Y = which ? y2 : y1;
    const long pstride = (long)NR * CC;

    const int per = (KT / 64) / ZKS;            // 18 or 12
    const int it0 = ks * per;

    f32x4 acc[4][4] = {};

    for (int it = it0; it < it0 + per; ++it) {
        const int k0 = it * 64;
        int tap = k0 / CIN;
        int kloc = k0 - tap * CIN;
        int plane = kloc >> 8, cip = kloc & 255;
        int dh = tap / 3 - 1, dw = tap - (tap / 3) * 3 - 1;
        int off = dh * 60 + dw;
        const u16* src = (plane == 0) ? P0 : ((plane == 1) ? P1 : P2);
        src += (long)b * pstride + cip;

#pragma unroll
        for (int i = 0; i < 4; ++i) {
            int idx = i * 256 + t;
            int row = idx >> 3, c8 = (idx & 7) * 8;
            uint4 v = *(const uint4*)(W + (long)(m0 + row) * KT + k0 + c8);
            *(uint4*)(&As[row * LDT + c8]) = v;
            int p = n0 + row;
            uint4 bv = make_uint4(0u, 0u, 0u, 0u);
            if (p < NN) {
                int h = p / 60, wp = p - h * 60;
                int hh = h + dh, wq = wp + dw;
                if (hh >= 0 && hh < 60 && wq >= 0 && wq < 60)
                    bv = *(const uint4*)(src + (long)(p + off) * CC + c8);
            }
            *(uint4*)(&Bs[row * LDT + c8]) = bv;
        }
        __syncthreads();
#pragma unroll
        for (int s = 0; s < 2; ++s) {
            short8 a[4], bfr[4];
#pragma unroll
            for (int i = 0; i < 4; ++i)
                a[i] = *(const short8*)(&As[(mh + i * 16 + lm) * LDT + s * 32 + quad * 8]);
#pragma unroll
            for (int j = 0; j < 4; ++j)
                bfr[j] = *(const short8*)(&Bs[(nh + j * 16 + lm) * LDT + s * 32 + quad * 8]);
#pragma unroll
            for (int i = 0; i < 4; ++i)
#pragma unroll
                for (int j = 0; j < 4; ++j)
                    acc[i][j] = __builtin_amdgcn_mfma_f32_16x16x32_bf16(a[i], bfr[j], acc[i][j], 0, 0, 0);
        }
        __syncthreads();
    }

    float* out = Y + (long)b * CC * NN;
#pragma unroll
    for (int i = 0; i < 4; ++i)
#pragma unroll
        for (int r = 0; r < 4; ++r) {
            int row = m0 + mh + i * 16 + quad * 4 + r;
#pragma unroll
            for (int j = 0; j < 4; ++j) {
                int col = n0 + nh + j * 16 + lm;
                if (col < NN)
                    atomicAdd(&out[(long)row * NN + col], acc[i][j][r]);
            }
        }
}

// ---------------------------------------------------------------------------
// Converters / transposes
// ---------------------------------------------------------------------------
__global__ __launch_bounds__(256)
void cvt_we(const float* __restrict__ W, u16* __restrict__ O)
{
    int i = blockIdx.x * 256 + threadIdx.x;
    if (i < CC * CC) O[i] = f2bf(W[i]);
}

// V [b][256][3600] fp32 -> VT [b][3712][256] bf16; optionally also the
// NP-padded bf16 copy Vpad [b][256][3648] (zeros in pad).
__global__ __launch_bounds__(256)
void transpose_cvt(const float* __restrict__ V, u16* __restrict__ VT,
                   u16* __restrict__ Vpad)
{
    __shared__ float tile[64][65];
    int b = blockIdx.z, c0 = blockIdx.y * 64, n0 = blockIdx.x * 64;
    int t = threadIdx.x;
#pragma unroll
    for (int e = 0; e < 16; ++e) {
        int f = e * 256 + t; int i = f >> 6, j = f & 63;
        int n = n0 + j;
        float v = 0.f;
        if (n < NN) v = V[((long)b * CC + c0 + i) * NN + n];
        tile[i][j] = v;
        if (Vpad) Vpad[((long)b * CC + c0 + i) * NP + n] = f2bf(v);
    }
    __syncthreads();
#pragma unroll
    for (int e = 0; e < 16; ++e) {
        int f = e * 256 + t; int i = f >> 6, j = f & 63;
        int n = n0 + i;
        if (n < NN) VT[((long)b * NR + n) * CC + c0 + j] = f2bf(tile[j][i]);
    }
}

// Z fp32 [b][c][p] * sg[b][p] -> ZT bf16 [b][p][c]
__global__ __launch_bounds__(256)
void transpose_gate(const float* __restrict__ Z, const float* __restrict__ sg,
                    u16* __restrict__ ZT)
{
    __shared__ float tile[64][65];
    int b = blockIdx.z, c0 = blockIdx.y * 64, n0 = blockIdx.x * 64;
    int t = threadIdx.x;
#pragma unroll
    for (int e = 0; e < 16; ++e) {
        int f = e * 256 + t; int i = f >> 6, j = f & 63;
        int n = n0 + j;
        float v = 0.f;
        if (n < NN) v = Z[((long)b * CC + c0 + i) * NN + n];
        tile[i][j] = v;
    }
    __syncthreads();
#pragma unroll
    for (int e = 0; e < 16; ++e) {
        int f = e * 256 + t; int i = f >> 6, j = f & 63;
        int n = n0 + i;
        if (n < NN)
            ZT[((long)b * NR + n) * CC + c0 + j] = f2bf(tile[j][i] * sg[b * NN + n]);
    }
}

template<int CIN>
__global__ __launch_bounds__(256)
void cvt_convw(const float* __restrict__ W, u16* __restrict__ O)
{
    const int KT = 9 * CIN;
    long idx = (long)blockIdx.x * 256 + threadIdx.x;
    if (idx >= (long)CC * KT) return;
    int co = (int)(idx / KT);
    int r = (int)(idx % KT);
    int tap = r / CIN, ci = r % CIN;
    O[idx] = f2bf(W[((long)co * CIN + ci) * 9 + tap]);
}

// ---------------------------------------------------------------------------
// Per-pixel gate sigmoid: sg[b][p] = sigmoid(sum_c gw[c]*Z[c,p])
// ---------------------------------------------------------------------------
__global__ __launch_bounds__(256)
void gate_sig(const float* __restrict__ Z, const float* __restrict__ gw,
              float* __restrict__ sg)
{
    int t = threadIdx.x;
    int px = t & 63, ck = t >> 6;
    int b = blockIdx.y;
    int p = blockIdx.x * 64 + px;
    const float* Zp = Z + (long)b * CC * NN;
    float g = 0.f;
    if (p < NN) {
        for (int c = ck * 64; c < ck * 64 + 64; ++c) g += gw[c] * Zp[(long)c * NN + p];
    }
    __shared__ float red[256];
    red[t] = g;
    __syncthreads();
    if (t < 64) {
        int pp = blockIdx.x * 64 + t;
        if (pp < NN) {
            float tot = red[t] + red[t + 64] + red[t + 128] + red[t + 192];
            sg[b * NN + pp] = 1.f / (1.f + __expf(-tot));
        }
    }
}

// ---------------------------------------------------------------------------
// BatchNorm batch-stats -> scale/shift
// ---------------------------------------------------------------------------
__global__ __launch_bounds__(256)
void bn_stats_kernel(const float* __restrict__ Y, const float* __restrict__ g,
                     const float* __restrict__ beta, float* __restrict__ scale,
                     float* __restrict__ shift)
{
    int c = blockIdx.x, t = threadIdx.x;
    float s = 0.f, sq = 0.f;
    for (int b = 0; b < BB; ++b) {
        const float* p = Y + (long)b * CC * NN + (long)c * NN;
        for (int i = t; i < NN; i += 256) { float v = p[i]; s += v; sq += v * v; }
    }
    __shared__ float ls[256], lq[256];
    ls[t] = s; lq[t] = sq;
    __syncthreads();
    for (int off = 128; off > 0; off >>= 1) {
        if (t < off) { ls[t] += ls[t + off]; lq[t] += lq[t + off]; }
        __syncthreads();
    }
    if (t == 0) {
        const float inv = 1.f / (float)(BB * NN);
        float mean = ls[0] * inv;
        float var = fmaxf(lq[0] * inv - mean * mean, 0.f);
        float sc = g[c] * rsqrtf(var + 1e-5f);
        scale[c] = sc;
        shift[c] = beta[c] - mean * sc;
    }
}

// ---------------------------------------------------------------------------
// Fused BN-normalize + ReLU + 1x1 cls conv + bias
// ---------------------------------------------------------------------------
__global__ __launch_bounds__(256)
void cls_kernel(const float* __restrict__ Y, const float* __restrict__ scale,
                const float* __restrict__ shift, const float* __restrict__ cw,
                const float* __restrict__ cb, float* __restrict__ O)
{
    int t = threadIdx.x;
    int px = t & 63, ck = t >> 6;
    int b = blockIdx.y;
    int p = blockIdx.x * 64 + px;
    const float* Yb = Y + (long)b * CC * NN;
    float a0 = 0.f, a1 = 0.f;
    if (p < NN) {
        for (int c = ck * 64; c < ck * 64 + 64; ++c) {
            float v = Yb[(long)c * NN + p] * scale[c] + shift[c];
            v = fmaxf(v, 0.f);
            a0 += cw[c] * v;
            a1 += cw[CC + c] * v;
        }
    }
    __shared__ float r0[256], r1[256];
    r0[t] = a0; r1[t] = a1;
    __syncthreads();
    if (t < 64) {
        int pp = blockIdx.x * 64 + t;
        if (pp < NN) {
            float s0 = r0[t] + r0[t + 64] + r0[t + 128] + r0[t + 192];
            float s1 = r1[t] + r1[t + 64] + r1[t + 128] + r1[t + 192];
            O[(long)b * NCH * NN + pp] = s0 + cb[0];
            O[(long)b * NCH * NN + NN + pp] = s1 + cb[1];
        }
    }
}

// ---------------------------------------------------------------------------
// Bilinear resize 60x60 -> 473x473 (half-pixel, clamp) + sigmoid
// ---------------------------------------------------------------------------
__global__ __launch_bounds__(256)
void resize_sig_kernel(const float* __restrict__ I1, const float* __restrict__ I2,
                       float* __restrict__ O)
{
    const long HALF = (long)BB * NCH * HO * WO;
    long gid = (long)blockIdx.x * 256 + threadIdx.x;
    if (gid >= HALF) return;
    int half = blockIdx.y;
    const float* I = half ? I2 : I1;
    float* Op = O + half * HALF;

    int j = (int)(gid % WO);
    long r = gid / WO;
    int i = (int)(r % HO);
    int pc = (int)(r / HO);
    const float* ip = I + (long)pc * NN;

    const float SCL = 60.0f / 473.0f;
    float fy = (i + 0.5f) * SCL - 0.5f;
    float fx = (j + 0.5f) * SCL - 0.5f;
    int y0 = (int)floorf(fy);
    int x0 = (int)floorf(fx);
    float ty = fy - (float)y0;
    float tx = fx - (float)x0;
    int y0c = max(y0, 0), y1c = min(y0 + 1, 59);
    int x0c = max(x0, 0), x1c = min(x0 + 1, 59);
    float va = ip[y0c * 60 + x0c], vb = ip[y0c * 60 + x1c];
    float vc = ip[y1c * 60 + x0c], vd = ip[y1c * 60 + x1c];
    float v = (1.f - ty) * ((1.f - tx) * va + tx * vb) + ty * ((1.f - tx) * vc + tx * vd);
    Op[gid] = 1.f / (1.f + __expf(-v));
}

// ---------------------------------------------------------------------------
extern "C" void kernel_launch(void* const* d_in, const int* in_sizes, int n_in,
                              void* d_out, int out_size, void* d_ws, size_t ws_size,
                              hipStream_t stream)
{
    const float* V_a    = (const float*)d_in[0];
    const float* V_b    = (const float*)d_in[1];
    const float* D_a    = (const float*)d_in[2];
    const float* W_e    = (const float*)d_in[3];
    const float* gate_w = (const float*)d_in[4];
    const float* conv1_w = (const float*)d_in[5];
    const float* conv2_w = (const float*)d_in[6];
    const float* bn1_g = (const float*)d_in[7];
    const float* bn1_b = (const float*)d_in[8];
    const float* bn2_g = (const float*)d_in[9];
    const float* bn2_b = (const float*)d_in[10];
    const float* cls1_w = (const float*)d_in[11];
    const float* cls1_b = (const float*)d_in[12];
    const float* cls2_w = (const float*)d_in[13];
    const float* cls2_b = (const float*)d_in[14];
    float* out = (float*)d_out;

    // ---- workspace arena: ~143 MB (known-safe bound: 154.9 MB) ----
    size_t off = 0;
    char* wsb = (char*)d_ws;
    auto carve = [&](size_t bytes) -> char* {
        char* p = wsb + off; off += (bytes + 255) & ~(size_t)255; return p;
    };

    u16* Sh    = (u16*)carve((size_t)NN * NP * 2);         // 26.3 MB, per-batch
    u16* STh   = (u16*)carve((size_t)NN * NP * 2);         // 26.3 MB, per-batch
    u16* vab   = (u16*)carve((size_t)BB * CC * NP * 2);
    u16* vbb   = (u16*)carve((size_t)BB * CC * NP * 2);
    u16* vat   = (u16*)carve((size_t)BB * NR * CC * 2);
    u16* vbt   = (u16*)carve((size_t)BB * NR * CC * 2);
    u16* daT   = (u16*)carve((size_t)BB * NR * CC * 2);
    u16* gzaT  = (u16*)carve((size_t)BB * NR * CC * 2);
    u16* gzbT  = (u16*)carve((size_t)BB * NR * CC * 2);
    u16* wgtb  = (u16*)carve((size_t)BB * NR * CC * 2);
    u16* web   = (u16*)carve((size_t)CC * CC * 2);
    u16* wt1   = (u16*)carve((size_t)CC * 9 * 768 * 2);
    u16* wt2   = (u16*)carve((size_t)CC * 9 * 512 * 2);
    float* Za  = (float*)carve((size_t)BB * CC * NN * 4);  // contiguous 4-block
    float* Zb  = (float*)carve((size_t)BB * CC * NN * 4);  //   memset region
    float* y1  = (float*)carve((size_t)BB * CC * NN * 4);
    float* y2  = (float*)carve((size_t)BB * CC * NN * 4);
    float* rmx = (float*)carve((size_t)BB * NN * 4);
    float* rsm = (float*)carve((size_t)BB * NN * 4);
    float* cmx = (float*)carve((size_t)BB * NN * 4);
    float* csm = (float*)carve((size_t)BB * NN * 4);
    float* sga = (float*)carve((size_t)BB * NN * 4);
    float* sgb = (float*)carve((size_t)BB * NN * 4);
    float* prm = (float*)carve((size_t)NTI * NR * 4);
    float* prs = (float*)carve((size_t)NTI * NR * 4);
    float* pcm = (float*)carve((size_t)NTI * NR * 4);
    float* pcs = (float*)carve((size_t)NTI * NR * 4);
    float* c1o = (float*)carve((size_t)BB * NCH * NN * 4);
    float* c2o = (float*)carve((size_t)BB * NCH * NN * 4);

    dim3 blk(256);

    // zero-init all atomic accumulators (Za,Zb,y1,y2 contiguous)
    hipMemsetAsync(Za, 0, (size_t)4 * BB * CC * NN * 4, stream);

    // --- input conversions (padded copies fused into transposes) ---
    cvt_we<<<256, blk, 0, stream>>>(W_e, web);
    transpose_cvt<<<dim3(57, 4, BB), blk, 0, stream>>>(V_a, vat, vab);
    transpose_cvt<<<dim3(57, 4, BB), blk, 0, stream>>>(V_b, vbt, vbb);
    transpose_cvt<<<dim3(57, 4, BB), blk, 0, stream>>>(D_a, daT, nullptr);
    cvt_convw<768><<<(int)(((long)CC * 9 * 768 + 255) / 256), blk, 0, stream>>>(conv1_w, wt1);
    cvt_convw<512><<<(int)(((long)CC * 9 * 512 + 255) / 256), blk, 0, stream>>>(conv2_w, wt2);

    // --- weighted (both batches) ---
    gemm_we<<<dim3(2, NTI, BB), blk, 0, stream>>>(vat, web, wgtb);

    // --- attention, per batch ---
    for (int b = 0; b < BB; ++b) {
        const u16* wgtb_b = wgtb + (long)b * NR * CC;
        const u16* vbt_b  = vbt + (long)b * NR * CC;
        const u16* vab_b  = vab + (long)b * CC * NP;
        const u16* vbb_b  = vbb + (long)b * CC * NP;
        float* rmx_b = rmx + b * NN; float* rsm_b = rsm + b * NN;
        float* cmx_b = cmx + b * NN; float* csm_b = csm + b * NN;

        gemm_s_stats<<<dim3(NTI, NTI), blk, 0, stream>>>(
            wgtb_b, vbt_b, Sh, STh, prm, prs, pcm, pcs);
        stats_combine<<<dim3((NN + 255) / 256, 2), blk, 0, stream>>>(
            prm, prs, pcm, pcs, rmx_b, rsm_b, cmx_b, csm_b);
        p_build<<<dim3(NN, 2), blk, 0, stream>>>(Sh, STh, rmx_b, rsm_b, cmx_b, csm_b);
        gemm_z_128<<<dim3(NTI, ZKS, 4), blk, 0, stream>>>(
            vab_b, vbb_b, STh, Sh,
            Zb + (long)b * CC * NN, Za + (long)b * CC * NN);
    }

    // --- gates: per-pixel sigmoid, then transpose-scale to [p][c] bf16 ---
    gate_sig<<<dim3(57, BB), blk, 0, stream>>>(Za, gate_w, sga);
    gate_sig<<<dim3(57, BB), blk, 0, stream>>>(Zb, gate_w, sgb);
    transpose_gate<<<dim3(57, 4, BB), blk, 0, stream>>>(Za, sga, gzaT);
    transpose_gate<<<dim3(57, 4, BB), blk, 0, stream>>>(Zb, sgb, gzbT);

    // --- both convs, one launch, XCD-grouped remap, atomic into y1/y2 ---
    conv_both<<<dim3(NTI, ZKS, 8), blk, 0, stream>>>(
        wt1, wt2, gzaT, vat, daT, gzbT, vbt, y1, y2);

    // --- BN + cls + resize --- (rmx/rsm/cmx/csm reused as scale/shift)
    bn_stats_kernel<<<256, blk, 0, stream>>>(y1, bn1_g, bn1_b, rmx, rsm);
    bn_stats_kernel<<<256, blk, 0, stream>>>(y2, bn2_g, bn2_b, cmx, csm);
    cls_kernel<<<dim3(57, BB), blk, 0, stream>>>(y1, rmx, rsm, cls1_w, cls1_b, c1o);
    cls_kernel<<<dim3(57, BB), blk, 0, stream>>>(y2, cmx, csm, cls2_w, cls2_b, c2o);

    resize_sig_kernel<<<dim3((int)(((long)BB * NCH * HO * WO + 255) / 256), 2), blk, 0, stream>>>(c1o, c2o, out);
}